// Round 1
// baseline (555.696 us; speedup 1.0000x reference)
//
#include <hip/hip_runtime.h>
#include <cstdint>
#include <cstddef>

#define IN_F   4096
#define OUT_F  4096
#define NTOK   8192
#define NGRP   32

#define BM 128
#define BN 128
#define BK 32

typedef __attribute__((ext_vector_type(8))) __bf16 bf16x8;
typedef __attribute__((ext_vector_type(4))) float  floatx4;

// fp32 -> bf16 bits, round-to-nearest-even (inputs are finite; no NaN handling)
__device__ __forceinline__ unsigned short f2bf(float f) {
    unsigned int u = __builtin_bit_cast(unsigned int, f);
    u += 0x7fffu + ((u >> 16) & 1u);
    return (unsigned short)(u >> 16);
}

// async global -> LDS, 16B per lane. LDS dest is wave-uniform base + lane*16.
__device__ __forceinline__ void gload16(const void* g, void* l) {
    __builtin_amdgcn_global_load_lds(
        (const __attribute__((address_space(1))) void*)g,
        (__attribute__((address_space(3))) void*)l,
        16, 0, 0);
}

// ---------------------------------------------------------------------------
// 1) Dequant: qweight [K/8][N] int32 (8 nibbles along K) -> Wt [N][K] bf16
//    W[k][n] = scales[g(k)][n] * ((qw[k/8][n]>>4*(k%8)&15) - ((qz[g][n/8]>>4*(n%8)&15)+1))
//    Thread t handles one (n, k8): writes 8 consecutive k as one 16B store.
//    Lanes sweep k8 fastest -> fully coalesced 16B writes.
// ---------------------------------------------------------------------------
__global__ void dequant_kernel(const int* __restrict__ qweight,
                               const int* __restrict__ qzeros,
                               const float* __restrict__ scales,
                               const int* __restrict__ g_idx,
                               unsigned short* __restrict__ Wt) {
    const int t  = blockIdx.x * 256 + threadIdx.x;   // 4096*512 threads
    const int n  = t >> 9;          // 0..4095
    const int k8 = t & 511;         // 0..511
    const int k  = k8 * 8;

    const int g  = g_idx[k];                         // group (uniform over k..k+7)
    const int qw = qweight[(size_t)k8 * OUT_F + n];
    const int zw = qzeros[g * (OUT_F / 8) + (n >> 3)];
    const int z  = ((zw >> (4 * (n & 7))) & 15) + 1;
    const float s = scales[g * OUT_F + n];
    const float sz = s * (float)z;

    union { unsigned short h[8]; uint4 v; } u;
#pragma unroll
    for (int j = 0; j < 8; ++j) {
        const int q = (qw >> (4 * j)) & 15;
        u.h[j] = f2bf(s * (float)q - sz);
    }
    *(uint4*)(Wt + (size_t)n * IN_F + k) = u.v;
}

// ---------------------------------------------------------------------------
// 2) x fp32 -> bf16, 8 elements/thread
// ---------------------------------------------------------------------------
__global__ void xcast_kernel(const float* __restrict__ x,
                             unsigned short* __restrict__ Xb) {
    const size_t i = ((size_t)blockIdx.x * 256 + threadIdx.x) * 8;
    const float4 a = *(const float4*)(x + i);
    const float4 b = *(const float4*)(x + i + 4);
    union { unsigned short h[8]; uint4 v; } u;
    u.h[0] = f2bf(a.x); u.h[1] = f2bf(a.y); u.h[2] = f2bf(a.z); u.h[3] = f2bf(a.w);
    u.h[4] = f2bf(b.x); u.h[5] = f2bf(b.y); u.h[6] = f2bf(b.z); u.h[7] = f2bf(b.w);
    *(uint4*)(Xb + i) = u.v;
}

// ---------------------------------------------------------------------------
// 3) GEMM: out[M][N] = Xb[M][K] * Wt[N][K]^T + bias
//    m97 structure: 128x128 tile, BK=32, 4 waves (2x2) of 64x64 each,
//    4x4 fragments of mfma_f32_16x16x32_bf16, global_load_lds width=16.
// ---------------------------------------------------------------------------
__global__ void gemm_kernel(const unsigned short* __restrict__ Xb,
                            const unsigned short* __restrict__ Wt,
                            const float* __restrict__ bias,
                            float* __restrict__ out) {
    __shared__ unsigned short As[BM * BK];   // [128 rows][32 k] bf16, 64B/row
    __shared__ unsigned short Bs[BN * BK];   // [128 n  ][32 k]

    const int tid  = threadIdx.x;
    const int wave = tid >> 6;          // 0..3
    const int lane = tid & 63;
    const int wm   = (wave >> 1) * 64;  // wave tile origin in block tile
    const int wn   = (wave & 1) * 64;
    const int m0   = blockIdx.y * BM;
    const int n0   = blockIdx.x * BN;

    // staging: each gload16 call covers 1024B = 16 rows x 64B
    const int sr = lane >> 2;   // row within 16-row chunk
    const int sc = lane & 3;    // 16B chunk within row

    // fragment indices
    const int mi = lane & 15;
    const int kq = lane >> 4;

    floatx4 acc[4][4];
#pragma unroll
    for (int i = 0; i < 4; ++i)
#pragma unroll
        for (int j = 0; j < 4; ++j)
            acc[i][j] = floatx4{0.f, 0.f, 0.f, 0.f};

    const unsigned short* Ag = Xb + (size_t)m0 * IN_F;
    const unsigned short* Bg = Wt + (size_t)n0 * IN_F;

    for (int k0 = 0; k0 < IN_F; k0 += BK) {
        __syncthreads();   // previous iter's LDS reads done before overwrite
#pragma unroll
        for (int c = 0; c < 2; ++c) {
            const int q   = wave * 2 + c;     // 16-row chunk id, 0..7
            const int row = q * 16 + sr;
            gload16(Ag + (size_t)row * IN_F + k0 + sc * 8, (void*)(As + q * 16 * BK));
            gload16(Bg + (size_t)row * IN_F + k0 + sc * 8, (void*)(Bs + q * 16 * BK));
        }
        __syncthreads();   // drains vmcnt (global_load_lds) + barrier

        bf16x8 av[4], bv[4];
#pragma unroll
        for (int i = 0; i < 4; ++i)
            av[i] = *(const bf16x8*)(As + (wm + i * 16 + mi) * BK + kq * 8);
#pragma unroll
        for (int j = 0; j < 4; ++j)
            bv[j] = *(const bf16x8*)(Bs + (wn + j * 16 + mi) * BK + kq * 8);
#pragma unroll
        for (int i = 0; i < 4; ++i)
#pragma unroll
            for (int j = 0; j < 4; ++j)
                acc[i][j] = __builtin_amdgcn_mfma_f32_16x16x32_bf16(
                    av[i], bv[j], acc[i][j], 0, 0, 0);
    }

    // epilogue: C/D layout col = lane&15, row = (lane>>4)*4 + reg  [m89/m91]
    const int mq = lane >> 4;
#pragma unroll
    for (int j = 0; j < 4; ++j) {
        const int col = n0 + wn + j * 16 + mi;
        const float bb = bias[col];
#pragma unroll
        for (int i = 0; i < 4; ++i) {
#pragma unroll
            for (int r = 0; r < 4; ++r) {
                const int row = m0 + wm + i * 16 + mq * 4 + r;
                out[(size_t)row * OUT_F + col] = acc[i][j][r] + bb;
            }
        }
    }
}

// ---------------------------------------------------------------------------
extern "C" void kernel_launch(void* const* d_in, const int* in_sizes, int n_in,
                              void* d_out, int out_size, void* d_ws, size_t ws_size,
                              hipStream_t stream) {
    const float* x       = (const float*)d_in[0];
    const int*   qweight = (const int*)d_in[1];
    const int*   qzeros  = (const int*)d_in[2];
    const float* scales  = (const float*)d_in[3];
    const int*   g_idx   = (const int*)d_in[4];
    const float* bias    = (const float*)d_in[5];
    float*       out     = (float*)d_out;

    // workspace layout: Wt bf16 [4096][4096] (32 MiB) | Xb bf16 [8192][4096] (64 MiB)
    unsigned short* Wt = (unsigned short*)d_ws;
    unsigned short* Xb = Wt + (size_t)OUT_F * IN_F;

    dequant_kernel<<<(OUT_F * (IN_F / 8)) / 256, 256, 0, stream>>>(
        qweight, qzeros, scales, g_idx, Wt);
    xcast_kernel<<<((size_t)NTOK * IN_F / 8) / 256, 256, 0, stream>>>(x, Xb);

    dim3 grid(OUT_F / BN, NTOK / BM);   // (32, 64)
    gemm_kernel<<<grid, 256, 0, stream>>>(Xb, Wt, bias, out);
}

// Round 2
// 545.592 us; speedup vs baseline: 1.0185x; 1.0185x over previous
//
#include <hip/hip_runtime.h>
#include <cstdint>
#include <cstddef>

#define IN_F   4096
#define OUT_F  4096
#define NTOK   8192
#define NGRP   32

#define BM 128
#define BN 128
#define BK 32

typedef __attribute__((ext_vector_type(8))) __bf16 bf16x8;
typedef __attribute__((ext_vector_type(4))) float  floatx4;

// fp32 -> bf16 bits, round-to-nearest-even
__device__ __forceinline__ unsigned short f2bf(float f) {
    unsigned int u = __builtin_bit_cast(unsigned int, f);
    u += 0x7fffu + ((u >> 16) & 1u);
    return (unsigned short)(u >> 16);
}

// async global -> LDS, 16B per lane. LDS dest is wave-uniform base + lane*16.
__device__ __forceinline__ void gload16(const void* g, void* l) {
    __builtin_amdgcn_global_load_lds(
        (const __attribute__((address_space(1))) void*)g,
        (__attribute__((address_space(3))) void*)l,
        16, 0, 0);
}

// ---------------------------------------------------------------------------
// 1) Dequant: qweight [K/8][N] int32 (8 nibbles along K) -> Wt [N][K] bf16.
//    v2: coalesced reads (lanes sweep n), LDS transpose, coalesced 16B writes.
//    Block tile: k8 in [tk*8, tk*8+8)  x  n in [tn*256, tn*256+256).
//    LDS tile [256 n][64 halves], chunk position XOR-swizzled by (n&7):
//    both the transpose-in writes and transpose-out reads are conflict-free.
// ---------------------------------------------------------------------------
__global__ void dequant_kernel(const int* __restrict__ qweight,
                               const int* __restrict__ qzeros,
                               const float* __restrict__ scales,
                               const int* __restrict__ g_idx,
                               unsigned short* __restrict__ Wt) {
    __shared__ unsigned short tile[256 * 64];   // 32 KB
    const int tk  = blockIdx.x & 63;    // 64 k-tiles (8 k8-rows each)
    const int tn  = blockIdx.x >> 6;    // 16 n-tiles
    const int tid = threadIdx.x;
    const int n   = tn * 256 + tid;

#pragma unroll
    for (int r = 0; r < 8; ++r) {
        const int k8 = tk * 8 + r;
        const int k  = k8 * 8;
        const int g  = g_idx[k];                          // uniform -> scalar load
        const int qw = qweight[(size_t)k8 * OUT_F + n];   // lanes sweep n: coalesced
        const float s = scales[g * OUT_F + n];
        const int  zw = qzeros[g * (OUT_F / 8) + (n >> 3)];
        const float z = (float)(((zw >> (4 * (n & 7))) & 15) + 1);
        const float sz = s * z;
        union { unsigned short h[8]; uint4 v; } u;
#pragma unroll
        for (int j = 0; j < 8; ++j)
            u.h[j] = f2bf(s * (float)((qw >> (4 * j)) & 15) - sz);
        // chunk r stored at swizzled position r ^ (tid&7): conflict-free write
        *(uint4*)(tile + tid * 64 + ((r ^ (tid & 7)) * 8)) = u.v;
    }
    __syncthreads();
#pragma unroll
    for (int i = 0; i < 8; ++i) {
        const int nl = i * 32 + (tid >> 3);
        const int c  = tid & 7;
        const uint4 v = *(const uint4*)(tile + nl * 64 + ((c ^ (nl & 7)) * 8));
        *(uint4*)(Wt + (size_t)(tn * 256 + nl) * IN_F + tk * 64 + c * 8) = v;
    }
}

// ---------------------------------------------------------------------------
// 2) x fp32 -> bf16, 8 elements/thread
// ---------------------------------------------------------------------------
__global__ void xcast_kernel(const float* __restrict__ x,
                             unsigned short* __restrict__ Xb) {
    const size_t i = ((size_t)blockIdx.x * 256 + threadIdx.x) * 8;
    const float4 a = *(const float4*)(x + i);
    const float4 b = *(const float4*)(x + i + 4);
    union { unsigned short h[8]; uint4 v; } u;
    u.h[0] = f2bf(a.x); u.h[1] = f2bf(a.y); u.h[2] = f2bf(a.z); u.h[3] = f2bf(a.w);
    u.h[4] = f2bf(b.x); u.h[5] = f2bf(b.y); u.h[6] = f2bf(b.z); u.h[7] = f2bf(b.w);
    *(uint4*)(Xb + i) = u.v;
}

// ---------------------------------------------------------------------------
// 3) GEMM: out[M][N] = Xb[M][K] * Wt[N][K]^T + bias
//    m97 structure + XOR bank-conflict swizzle:
//    LDS rows are 64B (4 chunks of 16B); data chunk c of row r lives at
//    position c ^ ((r>>1)&3). Expressed on the staging side by permuting the
//    GLOBAL source address (global_load_lds pins LDS dest to base+lane*16).
//    Fragment reads then hit every bank exactly 2x (free) instead of 8-way.
// ---------------------------------------------------------------------------
__global__ void gemm_kernel(const unsigned short* __restrict__ Xb,
                            const unsigned short* __restrict__ Wt,
                            const float* __restrict__ bias,
                            float* __restrict__ out) {
    __shared__ unsigned short As[BM * BK];   // [128 rows][32 k] bf16, 64B/row
    __shared__ unsigned short Bs[BN * BK];

    const int tid  = threadIdx.x;
    const int wave = tid >> 6;
    const int lane = tid & 63;
    const int wm   = (wave >> 1) * 64;
    const int wn   = (wave & 1) * 64;
    const int m0   = blockIdx.y * BM;
    const int n0   = blockIdx.x * BN;

    // staging: each gload16 covers 1024B = 16 rows x 64B
    const int sr   = lane >> 2;                 // row within 16-row chunk
    const int sc   = lane & 3;                  // 16B chunk slot in LDS
    const int gch  = sc ^ ((sr >> 1) & 3);      // swizzled global chunk index

    // fragment indices
    const int mi = lane & 15;
    const int kq = lane >> 4;
    const int swz = (mi >> 1) & 3;              // row-swizzle for fragment reads

    floatx4 acc[4][4];
#pragma unroll
    for (int i = 0; i < 4; ++i)
#pragma unroll
        for (int j = 0; j < 4; ++j)
            acc[i][j] = floatx4{0.f, 0.f, 0.f, 0.f};

    const unsigned short* Ag = Xb + (size_t)m0 * IN_F;
    const unsigned short* Bg = Wt + (size_t)n0 * IN_F;

    for (int k0 = 0; k0 < IN_F; k0 += BK) {
        __syncthreads();
#pragma unroll
        for (int c = 0; c < 2; ++c) {
            const int q   = wave * 2 + c;       // 16-row chunk id, 0..7
            const int row = q * 16 + sr;
            gload16(Ag + (size_t)row * IN_F + k0 + gch * 8, (void*)(As + q * 16 * BK));
            gload16(Bg + (size_t)row * IN_F + k0 + gch * 8, (void*)(Bs + q * 16 * BK));
        }
        __syncthreads();

        bf16x8 av[4], bv[4];
#pragma unroll
        for (int i = 0; i < 4; ++i)
            av[i] = *(const bf16x8*)(As + (wm + i * 16 + mi) * BK + ((kq ^ swz) * 8));
#pragma unroll
        for (int j = 0; j < 4; ++j)
            bv[j] = *(const bf16x8*)(Bs + (wn + j * 16 + mi) * BK + ((kq ^ swz) * 8));
#pragma unroll
        for (int i = 0; i < 4; ++i)
#pragma unroll
            for (int j = 0; j < 4; ++j)
                acc[i][j] = __builtin_amdgcn_mfma_f32_16x16x32_bf16(
                    av[i], bv[j], acc[i][j], 0, 0, 0);
    }

    // epilogue: C/D layout col = lane&15, row = (lane>>4)*4 + reg  [m89/m91]
    const int mq = lane >> 4;
#pragma unroll
    for (int j = 0; j < 4; ++j) {
        const int col = n0 + wn + j * 16 + mi;
        const float bb = bias[col];
#pragma unroll
        for (int i = 0; i < 4; ++i) {
#pragma unroll
            for (int r = 0; r < 4; ++r) {
                const int row = m0 + wm + i * 16 + mq * 4 + r;
                out[(size_t)row * OUT_F + col] = acc[i][j][r] + bb;
            }
        }
    }
}

// ---------------------------------------------------------------------------
extern "C" void kernel_launch(void* const* d_in, const int* in_sizes, int n_in,
                              void* d_out, int out_size, void* d_ws, size_t ws_size,
                              hipStream_t stream) {
    const float* x       = (const float*)d_in[0];
    const int*   qweight = (const int*)d_in[1];
    const int*   qzeros  = (const int*)d_in[2];
    const float* scales  = (const float*)d_in[3];
    const int*   g_idx   = (const int*)d_in[4];
    const float* bias    = (const float*)d_in[5];
    float*       out     = (float*)d_out;

    unsigned short* Wt = (unsigned short*)d_ws;                 // 32 MiB
    unsigned short* Xb = Wt + (size_t)OUT_F * IN_F;             // 64 MiB

    dequant_kernel<<<64 * 16, 256, 0, stream>>>(qweight, qzeros, scales, g_idx, Wt);
    xcast_kernel<<<((size_t)NTOK * IN_F / 8) / 256, 256, 0, stream>>>(x, Xb);

    dim3 grid(OUT_F / BN, NTOK / BM);   // (32, 64)
    gemm_kernel<<<grid, 256, 0, stream>>>(Xb, Wt, bias, out);
}